// Round 1
// baseline (1540.741 us; speedup 1.0000x reference)
//
#include <hip/hip_runtime.h>
#include <cstddef>

#define NB 32
#define CC 64
#define TT 16
#define VV 256
#define KK 5

// ---------------------------------------------------------------------------
// Kernel 1: copy A -> d_out tail, and accumulate column sums for degree norm.
// grid (NB, 40), block 256. rows = K*V = 1280 per n, 32 rows per block.
__global__ __launch_bounds__(256) void k_copy_colsum(
    const float* __restrict__ A, float* __restrict__ outA, float* __restrict__ Dsum)
{
    int n = blockIdx.x, rb = blockIdx.y, w = threadIdx.x;
    size_t base = ((size_t)n * KK * VV + (size_t)rb * 32) * VV;
    float s = 0.f;
#pragma unroll
    for (int i = 0; i < 32; i++) {
        float val = A[base + i * VV + w];
        outA[base + i * VV + w] = val;
        s += val;
    }
    atomicAdd(&Dsum[n * VV + w], s);
}

// ---------------------------------------------------------------------------
// Kernel 2: xc[n,c,t,v] = sum_cin conv_w[c,cin]*x[n,cin,t,v] + conv_b[c]
// stored TRANSPOSED as xct[n][c][v][t] (t contiguous) for the fused kernel.
// grid (NB, 16 v-tiles), block 256.
__global__ __launch_bounds__(256) void k_xc(
    const float* __restrict__ x, const float* __restrict__ Wc,
    const float* __restrict__ bc, float* __restrict__ xct)
{
    __shared__ float Xs[64][16][16];  // [cin][t][v] 64 KB
    __shared__ float Wt[64][64];      // [cin][cout] 16 KB
    __shared__ float bs[64];
    int n = blockIdx.x, vt = blockIdx.y, tid = threadIdx.x;
    int v0 = vt * 16;

    for (int i = tid; i < 4096; i += 256)
        Wt[i >> 6][i & 63] = Wc[(i & 63) * 64 + (i >> 6)];
    if (tid < 64) bs[tid] = bc[tid];
    for (int i = tid; i < 16384; i += 256) {
        int v = i & 15, t = (i >> 4) & 15, cin = i >> 8;
        Xs[cin][t][v] = x[(((size_t)n * 64 + cin) * 16 + t) * 256 + v0 + v];
    }
    __syncthreads();

    int t = tid >> 4, vq = (tid >> 2) & 3, cg = tid & 3;
    for (int cqi = 0; cqi < 4; cqi++) {
        int c0 = (cqi * 4 + cg) * 4;
        float acc[4][4];
#pragma unroll
        for (int i = 0; i < 4; i++)
#pragma unroll
            for (int j = 0; j < 4; j++) acc[i][j] = bs[c0 + i];
        for (int cin = 0; cin < 64; cin++) {
            float4 xv4 = *(const float4*)&Xs[cin][t][vq * 4];
            float4 wv4 = *(const float4*)&Wt[cin][c0];
            float xv[4] = {xv4.x, xv4.y, xv4.z, xv4.w};
            float wv[4] = {wv4.x, wv4.y, wv4.z, wv4.w};
#pragma unroll
            for (int i = 0; i < 4; i++)
#pragma unroll
                for (int j = 0; j < 4; j++)
                    acc[i][j] = fmaf(wv[i], xv[j], acc[i][j]);
        }
#pragma unroll
        for (int i = 0; i < 4; i++)
#pragma unroll
            for (int j = 0; j < 4; j++)
                xct[(((size_t)n * 64 + c0 + i) * 256 + v0 + vq * 4 + j) * 16 + t] =
                    acc[i][j];
    }
}

// ---------------------------------------------------------------------------
// Kernel 3: fused per-(n, 16-w-tile) block:
//   Phase A: mask-selected 3-layer MLP on A[n,:,v,w] for a 16v x 16w chunk -> Ms (LDS)
//   Phase B: acc[c,t,w] += xct[n,c,v,t] * Ms[c,v,w]  (8t x 8w micro-tiles)
//   Epilogue: out = acc * Dl
// grid (NB, 16), block 256.
__global__ __launch_bounds__(256, 1) void k_fused(
    const float* __restrict__ A, const float* __restrict__ xct,
    const float* __restrict__ hm, const float* __restrict__ Dsum,
    const float* __restrict__ nh_w1, const float* __restrict__ nh_b1,
    const float* __restrict__ nh_w2, const float* __restrict__ nh_b2,
    const float* __restrict__ nh_w3, const float* __restrict__ nh_b3,
    const float* __restrict__ h_w1, const float* __restrict__ h_b1,
    const float* __restrict__ h_w2, const float* __restrict__ h_b2,
    const float* __restrict__ h_w3, const float* __restrict__ h_b3,
    float* __restrict__ out)
{
    constexpr int MST = 268;  // Ms leading stride (mod 32 = 12: spreads banks, 16B aligned)
    __shared__ float Wsh[2 * 2752];
    __shared__ float Ms[64 * MST];
    int n = blockIdx.x, wt = blockIdx.y, tid = threadIdx.x;

    // weight staging: per-branch layout [w1:0(80)][b1:80(16)][w2:96(512)][b2:608(32)]
    //                                   [w3:640(2048)][b3:2688(64)]  total 2752
    {
        const float* srcs[12] = {nh_w1, nh_b1, nh_w2, nh_b2, nh_w3, nh_b3,
                                 h_w1,  h_b1,  h_w2,  h_b2,  h_w3,  h_b3};
        const int offs[12] = {0, 80, 96, 608, 640, 2688,
                              2752, 2832, 2848, 3360, 3392, 5440};
        const int cnts[12] = {80, 16, 512, 32, 2048, 64, 80, 16, 512, 32, 2048, 64};
        for (int a = 0; a < 12; a++)
            for (int i = tid; i < cnts[a]; i += 256) Wsh[offs[a] + i] = srcs[a][i];
    }

    // Phase A role: one MLP point per thread per chunk
    int vl = tid >> 4, wl = tid & 15;
    int wg = wt * 16 + wl;
    // Phase B role: c = tid>>2, 8t x 8w micro-tile
    int c = tid >> 2, mt = (tid >> 1) & 1, mw = tid & 1;

    float acc[8][8];
#pragma unroll
    for (int i = 0; i < 8; i++)
#pragma unroll
        for (int j = 0; j < 8; j++) acc[i][j] = 0.f;

    __syncthreads();
    // human_mask==1 -> h branch; ==0 -> nh branch (masks are exact 0/1)
    const float* wb = (hm[n * 256 + wg] > 0.5f) ? (Wsh + 2752) : Wsh;

    for (int vc = 0; vc < 16; vc++) {
        int v0 = vc * 16;
        // ---------------- Phase A: MLP ----------------
        {
            int v = v0 + vl;
            float a[5];
#pragma unroll
            for (int k = 0; k < 5; k++)
                a[k] = A[(((size_t)n * 5 + k) * 256 + v) * 256 + wg];
            float h1[16];
#pragma unroll
            for (int o = 0; o < 16; o++) {
                float s = wb[80 + o];
#pragma unroll
                for (int k = 0; k < 5; k++) s = fmaf(wb[o * 5 + k], a[k], s);
                h1[o] = fmaxf(s, 0.f);
            }
            float h2[32];
#pragma unroll
            for (int o = 0; o < 32; o++) {
                float s = wb[608 + o];
                const float4* wr = (const float4*)(wb + 96 + o * 16);
#pragma unroll
                for (int q = 0; q < 4; q++) {
                    float4 w4 = wr[q];
                    s = fmaf(w4.x, h1[q * 4 + 0], s);
                    s = fmaf(w4.y, h1[q * 4 + 1], s);
                    s = fmaf(w4.z, h1[q * 4 + 2], s);
                    s = fmaf(w4.w, h1[q * 4 + 3], s);
                }
                h2[o] = fmaxf(s, 0.f);
            }
#pragma unroll
            for (int o = 0; o < 64; o++) {
                float s = wb[2688 + o];
                const float4* wr = (const float4*)(wb + 640 + o * 32);
#pragma unroll
                for (int q = 0; q < 8; q++) {
                    float4 w4 = wr[q];
                    s = fmaf(w4.x, h2[q * 4 + 0], s);
                    s = fmaf(w4.y, h2[q * 4 + 1], s);
                    s = fmaf(w4.z, h2[q * 4 + 2], s);
                    s = fmaf(w4.w, h2[q * 4 + 3], s);
                }
                Ms[o * MST + vl * 16 + wl] = fmaxf(s, 0.f);
            }
        }
        __syncthreads();
        // ---------------- Phase B: contraction ----------------
        {
            const float* xp = xct + (((size_t)n * 64 + c) * 256 + v0) * 16 + mt * 8;
#pragma unroll
            for (int v = 0; v < 16; v++) {
                float4 x0 = *(const float4*)(xp + v * 16);
                float4 x1 = *(const float4*)(xp + v * 16 + 4);
                float4 m0 = *(const float4*)&Ms[c * MST + v * 16 + mw * 8];
                float4 m1 = *(const float4*)&Ms[c * MST + v * 16 + mw * 8 + 4];
                float xv[8] = {x0.x, x0.y, x0.z, x0.w, x1.x, x1.y, x1.z, x1.w};
                float mv[8] = {m0.x, m0.y, m0.z, m0.w, m1.x, m1.y, m1.z, m1.w};
#pragma unroll
                for (int i = 0; i < 8; i++)
#pragma unroll
                    for (int j = 0; j < 8; j++)
                        acc[i][j] = fmaf(xv[i], mv[j], acc[i][j]);
            }
        }
        __syncthreads();
    }

    // ---------------- Epilogue: degree norm + store ----------------
    float dl[8];
#pragma unroll
    for (int j = 0; j < 8; j++)
        dl[j] = 1.f / (Dsum[n * 256 + wt * 16 + mw * 8 + j] + 0.001f);
#pragma unroll
    for (int i = 0; i < 8; i++) {
        size_t ob = (((size_t)n * 64 + c) * 16 + mt * 8 + i) * 256 + wt * 16 + mw * 8;
        float4 o0 = {acc[i][0] * dl[0], acc[i][1] * dl[1],
                     acc[i][2] * dl[2], acc[i][3] * dl[3]};
        float4 o1 = {acc[i][4] * dl[4], acc[i][5] * dl[5],
                     acc[i][6] * dl[6], acc[i][7] * dl[7]};
        *(float4*)&out[ob] = o0;
        *(float4*)&out[ob + 4] = o1;
    }
}

// ---------------------------------------------------------------------------
extern "C" void kernel_launch(void* const* d_in, const int* in_sizes, int n_in,
                              void* d_out, int out_size, void* d_ws, size_t ws_size,
                              hipStream_t stream)
{
    const float* x      = (const float*)d_in[0];
    const float* A      = (const float*)d_in[1];
    const float* hmask  = (const float*)d_in[2];
    // d_in[3] nonhuman_mask: implied by 1 - human_mask, unused
    const float* conv_w = (const float*)d_in[4];
    const float* conv_b = (const float*)d_in[5];
    const float* nh_w1 = (const float*)d_in[6];
    const float* nh_b1 = (const float*)d_in[7];
    const float* nh_w2 = (const float*)d_in[8];
    const float* nh_b2 = (const float*)d_in[9];
    const float* nh_w3 = (const float*)d_in[10];
    const float* nh_b3 = (const float*)d_in[11];
    const float* h_w1 = (const float*)d_in[12];
    const float* h_b1 = (const float*)d_in[13];
    const float* h_w2 = (const float*)d_in[14];
    const float* h_b2 = (const float*)d_in[15];
    const float* h_w3 = (const float*)d_in[16];
    const float* h_b3 = (const float*)d_in[17];

    float* out  = (float*)d_out;
    float* outA = out + (size_t)NB * CC * TT * VV;  // 8,388,608 offset

    float* Dsum = (float*)d_ws;                        // 32 KB
    float* xct  = (float*)((char*)d_ws + 32768);       // 33.5 MB, [n][c][v][t]

    hipMemsetAsync(Dsum, 0, NB * VV * sizeof(float), stream);
    k_copy_colsum<<<dim3(NB, (KK * VV) / 32), 256, 0, stream>>>(A, outA, Dsum);
    k_xc<<<dim3(NB, 16), 256, 0, stream>>>(x, conv_w, conv_b, xct);
    k_fused<<<dim3(NB, 16), 256, 0, stream>>>(
        A, xct, hmask, Dsum,
        nh_w1, nh_b1, nh_w2, nh_b2, nh_w3, nh_b3,
        h_w1, h_b1, h_w2, h_b2, h_w3, h_b3, out);
}

// Round 2
// 592.510 us; speedup vs baseline: 2.6004x; 2.6004x over previous
//
#include <hip/hip_runtime.h>
#include <hip/hip_bf16.h>
#include <cstddef>

#define NB 32
#define CC 64
#define TT 16
#define VV 256
#define KK 5

// ---------------------------------------------------------------------------
// K1: Dsum[n][w] = sum_{k,v} A[n,k,v,w].  grid (NB,40), block 256.
__global__ __launch_bounds__(256) void k_colsum(const float* __restrict__ A,
                                                float* __restrict__ Dsum)
{
    int n = blockIdx.x, rb = blockIdx.y, w = threadIdx.x;
    size_t base = ((size_t)n * (KK * VV) + rb * 32) * VV;
    float s = 0.f;
#pragma unroll
    for (int i = 0; i < 32; i++) s += A[base + i * VV + w];
    atomicAdd(&Dsum[n * VV + w], s);
}

// ---------------------------------------------------------------------------
// K2: xc[n,c,t,v] = sum_ci Wc[c,ci]*x[n,ci,t,v] + bc[c].  Natural layout out.
// grid (NB,16), block 256: thread = one (t,v) point, acc over all 64 c.
__global__ __launch_bounds__(256) void k_xc(const float* __restrict__ x,
                                            const float* __restrict__ Wc,
                                            const float* __restrict__ bc,
                                            float* __restrict__ xc)
{
    __shared__ float WT[64 * 64];  // WT[ci][co]
    __shared__ float bs[64];
    int n = blockIdx.x, tid = threadIdx.x;
    int p = blockIdx.y * 256 + tid;  // tv index
    for (int i = tid; i < 4096; i += 256) WT[(i & 63) * 64 + (i >> 6)] = Wc[i];
    if (tid < 64) bs[tid] = bc[tid];
    __syncthreads();

    float acc[64];
#pragma unroll
    for (int c = 0; c < 64; c++) acc[c] = bs[c];
#pragma unroll 4
    for (int ci = 0; ci < 64; ci++) {
        float xv = x[((size_t)n * 64 + ci) * 4096 + p];
        const float4* wr = (const float4*)&WT[ci * 64];
#pragma unroll
        for (int q = 0; q < 16; q++) {
            float4 w4 = wr[q];
            acc[q * 4 + 0] = fmaf(w4.x, xv, acc[q * 4 + 0]);
            acc[q * 4 + 1] = fmaf(w4.y, xv, acc[q * 4 + 1]);
            acc[q * 4 + 2] = fmaf(w4.z, xv, acc[q * 4 + 2]);
            acc[q * 4 + 3] = fmaf(w4.w, xv, acc[q * 4 + 3]);
        }
    }
#pragma unroll
    for (int c = 0; c < 64; c++) xc[((size_t)n * 64 + c) * 4096 + p] = acc[c];
}

// ---------------------------------------------------------------------------
// K3: M'[nl,c,v,w] = bf16( relu(MLP_sel(A[n,:,v,w])) * Dl[n,w] )
// grid (chunkN, 128), block 256: thread = (w = tid), 2 v-points.
__global__ __launch_bounds__(256) void k_mlp(
    const float* __restrict__ A, const float* __restrict__ hm,
    const float* __restrict__ Dsum,
    const float* __restrict__ nh_w1, const float* __restrict__ nh_b1,
    const float* __restrict__ nh_w2, const float* __restrict__ nh_b2,
    const float* __restrict__ nh_w3, const float* __restrict__ nh_b3,
    const float* __restrict__ h_w1, const float* __restrict__ h_b1,
    const float* __restrict__ h_w2, const float* __restrict__ h_b2,
    const float* __restrict__ h_w3, const float* __restrict__ h_b3,
    __hip_bfloat16* __restrict__ Mp, int n0)
{
    __shared__ float Wsh[2 * 2752];
    int tid = threadIdx.x;
    {
        const float* srcs[12] = {nh_w1, nh_b1, nh_w2, nh_b2, nh_w3, nh_b3,
                                 h_w1,  h_b1,  h_w2,  h_b2,  h_w3,  h_b3};
        const int offs[12] = {0, 80, 96, 608, 640, 2688,
                              2752, 2832, 2848, 3360, 3392, 5440};
        const int cnts[12] = {80, 16, 512, 32, 2048, 64, 80, 16, 512, 32, 2048, 64};
        for (int a = 0; a < 12; a++)
            for (int i = tid; i < cnts[a]; i += 256) Wsh[offs[a] + i] = srcs[a][i];
    }
    int nl = blockIdx.x, n = n0 + nl;
    int v0 = blockIdx.y * 2;
    int w = tid;
    __syncthreads();

    const float* wb = (hm[n * 256 + w] > 0.5f) ? (Wsh + 2752) : Wsh;
    float dl = 1.0f / (Dsum[n * 256 + w] + 0.001f);

    float a0[5], a1[5];
#pragma unroll
    for (int k = 0; k < 5; k++) {
        const float* ap = A + (((size_t)n * 5 + k) * 256 + v0) * 256 + w;
        a0[k] = ap[0];
        a1[k] = ap[256];
    }
    float h1a[16], h1b[16];
#pragma unroll
    for (int o = 0; o < 16; o++) {
        float s0 = wb[80 + o], s1 = s0;
#pragma unroll
        for (int k = 0; k < 5; k++) {
            float wv = wb[o * 5 + k];
            s0 = fmaf(wv, a0[k], s0);
            s1 = fmaf(wv, a1[k], s1);
        }
        h1a[o] = fmaxf(s0, 0.f);
        h1b[o] = fmaxf(s1, 0.f);
    }
    float h2a[32], h2b[32];
#pragma unroll 4
    for (int o = 0; o < 32; o++) {
        float s0 = wb[608 + o], s1 = s0;
        const float4* wr = (const float4*)(wb + 96 + o * 16);
#pragma unroll
        for (int q = 0; q < 4; q++) {
            float4 w4 = wr[q];
            s0 = fmaf(w4.x, h1a[q * 4 + 0], s0); s1 = fmaf(w4.x, h1b[q * 4 + 0], s1);
            s0 = fmaf(w4.y, h1a[q * 4 + 1], s0); s1 = fmaf(w4.y, h1b[q * 4 + 1], s1);
            s0 = fmaf(w4.z, h1a[q * 4 + 2], s0); s1 = fmaf(w4.z, h1b[q * 4 + 2], s1);
            s0 = fmaf(w4.w, h1a[q * 4 + 3], s0); s1 = fmaf(w4.w, h1b[q * 4 + 3], s1);
        }
        h2a[o] = fmaxf(s0, 0.f);
        h2b[o] = fmaxf(s1, 0.f);
    }
    __hip_bfloat16* mp = Mp + (((size_t)nl * 64 * 256) + v0) * 256 + w;
#pragma unroll 4
    for (int o = 0; o < 64; o++) {
        float s0 = wb[2688 + o], s1 = s0;
        const float4* wr = (const float4*)(wb + 640 + o * 32);
#pragma unroll
        for (int q = 0; q < 8; q++) {
            float4 w4 = wr[q];
            s0 = fmaf(w4.x, h2a[q * 4 + 0], s0); s1 = fmaf(w4.x, h2b[q * 4 + 0], s1);
            s0 = fmaf(w4.y, h2a[q * 4 + 1], s0); s1 = fmaf(w4.y, h2b[q * 4 + 1], s1);
            s0 = fmaf(w4.z, h2a[q * 4 + 2], s0); s1 = fmaf(w4.z, h2b[q * 4 + 2], s1);
            s0 = fmaf(w4.w, h2a[q * 4 + 3], s0); s1 = fmaf(w4.w, h2b[q * 4 + 3], s1);
        }
        s0 = fmaxf(s0, 0.f) * dl;
        s1 = fmaxf(s1, 0.f) * dl;
        mp[(size_t)o * 65536]       = __float2bfloat16(s0);
        mp[(size_t)o * 65536 + 256] = __float2bfloat16(s1);
    }
}

// ---------------------------------------------------------------------------
// K4: out[n,c,t,w] = sum_v xc[n,c,t,v] * M'[nl,c,v,w]   (Dl already folded)
// grid (chunkN*64*2): block = (nl, c, w-half). block 256: thread = 2t x 4w.
__global__ __launch_bounds__(256) void k_gemm(const __hip_bfloat16* __restrict__ Mp,
                                              const float* __restrict__ xc,
                                              float* __restrict__ out, int n0)
{
    __shared__ float xcs[256 * 20];  // [v][t], stride 20 (16B-aligned, conflict-lite)
    int bx = blockIdx.x;
    int wh = bx & 1, c = (bx >> 1) & 63, nl = bx >> 7;
    int n = n0 + nl;
    int tid = threadIdx.x;

    const float* xcp = xc + ((size_t)n * 64 + c) * 4096;
#pragma unroll
    for (int t = 0; t < 16; t++) xcs[tid * 20 + t] = xcp[t * 256 + tid];
    __syncthreads();

    int wl = tid & 31, tg = tid >> 5;
    int w4 = wh * 128 + wl * 4, t2 = tg * 2;
    const ushort* mp = (const ushort*)Mp + ((size_t)nl * 64 + c) * 65536 + w4;

    float acc0[4] = {0.f, 0.f, 0.f, 0.f};
    float acc1[4] = {0.f, 0.f, 0.f, 0.f};
#pragma unroll 8
    for (int v = 0; v < 256; v++) {
        ushort4 mu = *(const ushort4*)(mp + (size_t)v * 256);
        float m0 = __uint_as_float((unsigned)mu.x << 16);
        float m1 = __uint_as_float((unsigned)mu.y << 16);
        float m2 = __uint_as_float((unsigned)mu.z << 16);
        float m3 = __uint_as_float((unsigned)mu.w << 16);
        float2 xv = *(const float2*)&xcs[v * 20 + t2];
        acc0[0] = fmaf(xv.x, m0, acc0[0]); acc1[0] = fmaf(xv.y, m0, acc1[0]);
        acc0[1] = fmaf(xv.x, m1, acc0[1]); acc1[1] = fmaf(xv.y, m1, acc1[1]);
        acc0[2] = fmaf(xv.x, m2, acc0[2]); acc1[2] = fmaf(xv.y, m2, acc1[2]);
        acc0[3] = fmaf(xv.x, m3, acc0[3]); acc1[3] = fmaf(xv.y, m3, acc1[3]);
    }
    size_t ob = (((size_t)n * 64 + c) * 16 + t2) * 256 + w4;
    float4 o0 = {acc0[0], acc0[1], acc0[2], acc0[3]};
    float4 o1 = {acc1[0], acc1[1], acc1[2], acc1[3]};
    *(float4*)&out[ob] = o0;
    *(float4*)&out[ob + 256] = o1;
}

// ---------------------------------------------------------------------------
// K5: copy A -> out tail (after xc scratch in that region is done being read).
__global__ __launch_bounds__(256) void k_copyA(const float4* __restrict__ A,
                                               float4* __restrict__ dst)
{
    int i = blockIdx.x * 256 + threadIdx.x;
#pragma unroll
    for (int r = 0; r < 5; r++) {
        if (i < 2621440) dst[i] = A[i];
        i += 524288;
    }
}

// ---------------------------------------------------------------------------
extern "C" void kernel_launch(void* const* d_in, const int* in_sizes, int n_in,
                              void* d_out, int out_size, void* d_ws, size_t ws_size,
                              hipStream_t stream)
{
    const float* x      = (const float*)d_in[0];
    const float* A      = (const float*)d_in[1];
    const float* hmask  = (const float*)d_in[2];
    const float* conv_w = (const float*)d_in[4];
    const float* conv_b = (const float*)d_in[5];
    const float* nh_w1 = (const float*)d_in[6];
    const float* nh_b1 = (const float*)d_in[7];
    const float* nh_w2 = (const float*)d_in[8];
    const float* nh_b2 = (const float*)d_in[9];
    const float* nh_w3 = (const float*)d_in[10];
    const float* nh_b3 = (const float*)d_in[11];
    const float* h_w1 = (const float*)d_in[12];
    const float* h_b1 = (const float*)d_in[13];
    const float* h_w2 = (const float*)d_in[14];
    const float* h_b2 = (const float*)d_in[15];
    const float* h_w3 = (const float*)d_in[16];
    const float* h_b3 = (const float*)d_in[17];

    float* out  = (float*)d_out;
    float* outA = out + (size_t)NB * CC * TT * VV;  // 8,388,608
    float* xcBuf = outA;  // xc scratch lives in the A-output region until k_copyA

    float* Dsum = (float*)d_ws;  // 32 KB
    __hip_bfloat16* Mp = (__hip_bfloat16*)((char*)d_ws + 32768);

    // adaptive n-chunking of the materialized M' (bf16, 8,388,608 B per n)
    size_t perN = (size_t)CC * VV * VV * 2;
    size_t cap = (ws_size > 32768) ? (ws_size - 32768) / perN : 4;
    int chunk = (cap >= 32) ? 32 : (cap >= 16) ? 16 : (cap >= 8) ? 8 : 4;

    hipMemsetAsync(Dsum, 0, NB * VV * sizeof(float), stream);
    k_colsum<<<dim3(NB, 40), 256, 0, stream>>>(A, Dsum);
    k_xc<<<dim3(NB, 16), 256, 0, stream>>>(x, conv_w, conv_b, xcBuf);

    for (int n0 = 0; n0 < NB; n0 += chunk) {
        k_mlp<<<dim3(chunk, 128), 256, 0, stream>>>(
            A, hmask, Dsum,
            nh_w1, nh_b1, nh_w2, nh_b2, nh_w3, nh_b3,
            h_w1, h_b1, h_w2, h_b2, h_w3, h_b3, Mp, n0);
        k_gemm<<<dim3(chunk * 128), 256, 0, stream>>>(Mp, xcBuf, out, n0);
    }
    k_copyA<<<dim3(2048), 256, 0, stream>>>((const float4*)A, (float4*)outA);
}

// Round 3
// 491.435 us; speedup vs baseline: 3.1352x; 1.2057x over previous
//
#include <hip/hip_runtime.h>
#include <hip/hip_bf16.h>
#include <cstddef>

#define NB 32
#define CC 64
#define TT 16
#define VV 256
#define KK 5

typedef __attribute__((ext_vector_type(8))) short short8;
typedef __attribute__((ext_vector_type(4))) float f32x4;

// ---------------------------------------------------------------------------
// K1: Dsum[n][w] = sum_{k,v} A[n,k,v,w].  grid (NB,40), block 256.
__global__ __launch_bounds__(256) void k_colsum(const float* __restrict__ A,
                                                float* __restrict__ Dsum)
{
    int n = blockIdx.x, rb = blockIdx.y, w = threadIdx.x;
    size_t base = ((size_t)n * (KK * VV) + rb * 32) * VV;
    float s = 0.f;
#pragma unroll
    for (int i = 0; i < 32; i++) s += A[base + i * VV + w];
    atomicAdd(&Dsum[n * VV + w], s);
}

// ---------------------------------------------------------------------------
// K2: xcb[n,c,t,v] = bf16( sum_ci Wc[c,ci]*x[n,ci,t,v] + bc[c] )
// grid (NB,16), block 256: thread = one (t,v) point, all 64 c in registers.
__global__ __launch_bounds__(256) void k_xc(const float* __restrict__ x,
                                            const float* __restrict__ Wc,
                                            const float* __restrict__ bc,
                                            __hip_bfloat16* __restrict__ xcb)
{
    __shared__ float WT[64 * 64];  // WT[ci][co]
    __shared__ float bs[64];
    int n = blockIdx.x, tid = threadIdx.x;
    int p = blockIdx.y * 256 + tid;  // tv index
    for (int i = tid; i < 4096; i += 256) WT[(i & 63) * 64 + (i >> 6)] = Wc[i];
    if (tid < 64) bs[tid] = bc[tid];
    __syncthreads();

    float acc[64];
#pragma unroll
    for (int c = 0; c < 64; c++) acc[c] = bs[c];
#pragma unroll 4
    for (int ci = 0; ci < 64; ci++) {
        float xv = x[((size_t)n * 64 + ci) * 4096 + p];
        const float4* wr = (const float4*)&WT[ci * 64];
#pragma unroll
        for (int q = 0; q < 16; q++) {
            float4 w4 = wr[q];
            acc[q * 4 + 0] = fmaf(w4.x, xv, acc[q * 4 + 0]);
            acc[q * 4 + 1] = fmaf(w4.y, xv, acc[q * 4 + 1]);
            acc[q * 4 + 2] = fmaf(w4.z, xv, acc[q * 4 + 2]);
            acc[q * 4 + 3] = fmaf(w4.w, xv, acc[q * 4 + 3]);
        }
    }
#pragma unroll
    for (int c = 0; c < 64; c++)
        xcb[((size_t)n * 64 + c) * 4096 + p] = __float2bfloat16(acc[c]);
}

// ---------------------------------------------------------------------------
// K3: M'T[nl,c,w,v] = bf16( relu(MLP_sel(A[n,:,v,w])) * Dl[n,w] )
// One w PER WAVE (lanes = v) -> branch pointer wave-uniform -> weights via
// scalar loads (no LDS, no conflicts, no VALU issue for weights).
// grid (chunk, 64), block 256 = 4 waves = 4 w's. Each wave: 4 v-chunks of 64.
__global__ __launch_bounds__(256) void k_mlp(
    const float* __restrict__ A, const float* __restrict__ hm,
    const float* __restrict__ Dsum,
    const float* __restrict__ nh_w1, const float* __restrict__ nh_b1,
    const float* __restrict__ nh_w2, const float* __restrict__ nh_b2,
    const float* __restrict__ nh_w3, const float* __restrict__ nh_b3,
    const float* __restrict__ h_w1, const float* __restrict__ h_b1,
    const float* __restrict__ h_w2, const float* __restrict__ h_b2,
    const float* __restrict__ h_w3, const float* __restrict__ h_b3,
    __hip_bfloat16* __restrict__ Mp, int n0)
{
    int tid = threadIdx.x;
    int lane = tid & 63;
    int wid = tid >> 6;
    int nl = blockIdx.x, n = n0 + nl;
    int w = blockIdx.y * 4 + wid;

    int flag = (hm[n * 256 + w] > 0.5f) ? 1 : 0;
    flag = __builtin_amdgcn_readfirstlane(flag);
    const float* W1 = flag ? h_w1 : nh_w1;
    const float* B1 = flag ? h_b1 : nh_b1;
    const float* W2 = flag ? h_w2 : nh_w2;
    const float* B2 = flag ? h_b2 : nh_b2;
    const float* W3 = flag ? h_w3 : nh_w3;
    const float* B3 = flag ? h_b3 : nh_b3;

    float dl = 1.0f / (Dsum[n * 256 + w] + 0.001f);

    for (int vc = 0; vc < 4; vc++) {
        int v = vc * 64 + lane;
        float a[5];
#pragma unroll
        for (int k = 0; k < 5; k++)
            a[k] = A[(((size_t)n * 5 + k) * 256 + v) * 256 + w];

        float h1[16];
#pragma unroll
        for (int o = 0; o < 16; o++) {
            float s = B1[o];
#pragma unroll
            for (int k = 0; k < 5; k++) s = fmaf(W1[o * 5 + k], a[k], s);
            h1[o] = fmaxf(s, 0.f);
        }
        float h2[32];
#pragma unroll 8
        for (int o = 0; o < 32; o++) {
            float s = B2[o];
#pragma unroll
            for (int i = 0; i < 16; i++) s = fmaf(W2[o * 16 + i], h1[i], s);
            h2[o] = fmaxf(s, 0.f);
        }
        // L3 + transposed store: Mp[nl][c][w][v]
        __hip_bfloat16* mp = Mp + (((size_t)nl * 64 * 256 + w) * 256) + v;
#pragma unroll 8
        for (int o = 0; o < 64; o++) {
            float s = B3[o];
#pragma unroll
            for (int i = 0; i < 32; i++) s = fmaf(W3[o * 32 + i], h2[i], s);
            s = fmaxf(s, 0.f) * dl;
            mp[(size_t)o * 65536] = __float2bfloat16(s);
        }
    }
}

// ---------------------------------------------------------------------------
// K4 (MFMA): out[n,c,t,w] = sum_v xcb[n,c,t,v] * M'T[nl,c,w,v]
// Per block: one (n,c). 4 waves; wave wid covers w in [wid*64, wid*64+64),
// 4 w-tiles of 16. A/B fragments are direct 16B global loads. No LDS.
__global__ __launch_bounds__(256) void k_gemm(const __hip_bfloat16* __restrict__ Mp,
                                              const __hip_bfloat16* __restrict__ xcb,
                                              float* __restrict__ out, int n0)
{
    int tid = threadIdx.x;
    int lane = tid & 63;
    int wid = tid >> 6;
    int c = blockIdx.x;
    int nl = blockIdx.y, n = n0 + nl;
    int col = lane & 15;   // A: t-row, B: w-col, D: w-col
    int quad = lane >> 4;  // k-subrange selector

    const short* xp = (const short*)xcb +
                      (((size_t)n * 64 + c) * 16 + col) * 256 + quad * 8;
    const short* bp = (const short*)Mp +
                      (((size_t)nl * 64 + c) * 256 + wid * 64 + col) * 256 + quad * 8;

    f32x4 acc[4] = {{0.f, 0.f, 0.f, 0.f},
                    {0.f, 0.f, 0.f, 0.f},
                    {0.f, 0.f, 0.f, 0.f},
                    {0.f, 0.f, 0.f, 0.f}};
#pragma unroll
    for (int ks = 0; ks < 8; ks++) {
        short8 af = *(const short8*)(xp + ks * 32);
#pragma unroll
        for (int wt = 0; wt < 4; wt++) {
            short8 bf = *(const short8*)(bp + (size_t)wt * 16 * 256 + ks * 32);
            acc[wt] = __builtin_amdgcn_mfma_f32_16x16x32_bf16(af, bf, acc[wt], 0, 0, 0);
        }
    }
#pragma unroll
    for (int wt = 0; wt < 4; wt++)
#pragma unroll
        for (int r = 0; r < 4; r++)
            out[(((size_t)n * 64 + c) * 16 + quad * 4 + r) * 256 +
                wid * 64 + wt * 16 + col] = acc[wt][r];
}

// ---------------------------------------------------------------------------
// K5: copy A -> out tail.
__global__ __launch_bounds__(256) void k_copyA(const float4* __restrict__ A,
                                               float4* __restrict__ dst)
{
    int i = blockIdx.x * 256 + threadIdx.x;
#pragma unroll
    for (int r = 0; r < 5; r++) {
        if (i < 2621440) dst[i] = A[i];
        i += 524288;
    }
}

// ---------------------------------------------------------------------------
extern "C" void kernel_launch(void* const* d_in, const int* in_sizes, int n_in,
                              void* d_out, int out_size, void* d_ws, size_t ws_size,
                              hipStream_t stream)
{
    const float* x      = (const float*)d_in[0];
    const float* A      = (const float*)d_in[1];
    const float* hmask  = (const float*)d_in[2];
    const float* conv_w = (const float*)d_in[4];
    const float* conv_b = (const float*)d_in[5];
    const float* nh_w1 = (const float*)d_in[6];
    const float* nh_b1 = (const float*)d_in[7];
    const float* nh_w2 = (const float*)d_in[8];
    const float* nh_b2 = (const float*)d_in[9];
    const float* nh_w3 = (const float*)d_in[10];
    const float* nh_b3 = (const float*)d_in[11];
    const float* h_w1 = (const float*)d_in[12];
    const float* h_b1 = (const float*)d_in[13];
    const float* h_w2 = (const float*)d_in[14];
    const float* h_b2 = (const float*)d_in[15];
    const float* h_w3 = (const float*)d_in[16];
    const float* h_b3 = (const float*)d_in[17];

    float* out  = (float*)d_out;
    float* outA = out + (size_t)NB * CC * TT * VV;

    float* Dsum = (float*)d_ws;                                   // 32 KB
    __hip_bfloat16* xcb = (__hip_bfloat16*)((char*)d_ws + 32768); // 16.8 MB
    size_t xcbBytes = (size_t)NB * CC * TT * VV * 2;
    __hip_bfloat16* Mp = (__hip_bfloat16*)((char*)d_ws + 32768 + xcbBytes);

    size_t perN = (size_t)CC * VV * VV * 2;  // 8,388,608 B per n
    size_t fixed = 32768 + xcbBytes;
    int chunk = 4;
    if (ws_size >= fixed + 16 * perN) chunk = 16;       // 134 MB M' — LLC-resident
    else if (ws_size >= fixed + 8 * perN) chunk = 8;

    hipMemsetAsync(Dsum, 0, NB * VV * sizeof(float), stream);
    k_colsum<<<dim3(NB, 40), 256, 0, stream>>>(A, Dsum);
    k_xc<<<dim3(NB, 16), 256, 0, stream>>>(x, conv_w, conv_b, xcb);

    for (int n0 = 0; n0 < NB; n0 += chunk) {
        k_mlp<<<dim3(chunk, 64), 256, 0, stream>>>(
            A, hmask, Dsum,
            nh_w1, nh_b1, nh_w2, nh_b2, nh_w3, nh_b3,
            h_w1, h_b1, h_w2, h_b2, h_w3, h_b3, Mp, n0);
        k_gemm<<<dim3(CC, chunk), 256, 0, stream>>>(Mp, xcb, out, n0);
    }
    k_copyA<<<dim3(2048), 256, 0, stream>>>((const float4*)A, (float4*)outA);
}

// Round 4
// 410.680 us; speedup vs baseline: 3.7517x; 1.1966x over previous
//
#include <hip/hip_runtime.h>
#include <hip/hip_bf16.h>
#include <cstddef>

#define NB 32
#define CC 64
#define TT 16
#define VV 256
#define KK 5

typedef __attribute__((ext_vector_type(8))) short short8;
typedef __attribute__((ext_vector_type(4))) float f32x4;

union U16B { short8 s8; uint2 u2[2]; unsigned u[4]; unsigned short us[8]; };

__device__ inline unsigned short f2bf(float f) {
    unsigned u = __float_as_uint(f);
    return (unsigned short)((u + 0x7fffu + ((u >> 16) & 1u)) >> 16);
}
__device__ inline unsigned packbf(float a, float b) {
    return (unsigned)f2bf(a) | ((unsigned)f2bf(b) << 16);
}

// ---------------------------------------------------------------------------
// K1: copy A -> out tail AND Dsum[n][w] += sum_{rows} A (A read once).
// grid (NB, 40), block 256.
__global__ __launch_bounds__(256) void k_copyAcs(const float* __restrict__ A,
                                                 float* __restrict__ outA,
                                                 float* __restrict__ Dsum)
{
    int n = blockIdx.x, rb = blockIdx.y, w = threadIdx.x;
    size_t base = ((size_t)n * (KK * VV) + rb * 32) * VV;
    float s = 0.f;
#pragma unroll
    for (int i = 0; i < 32; i++) {
        float val = A[base + i * VV + w];
        outA[base + i * VV + w] = val;
        s += val;
    }
    atomicAdd(&Dsum[n * VV + w], s);
}

// ---------------------------------------------------------------------------
// K2: xcb[n,c,t,v] = bf16( sum_ci Wc[c,ci]*x[n,ci,t,v] + bc[c] )
// grid (NB,16), block 256: thread = one (t,v) point, all 64 c in registers.
__global__ __launch_bounds__(256) void k_xc(const float* __restrict__ x,
                                            const float* __restrict__ Wc,
                                            const float* __restrict__ bc,
                                            __hip_bfloat16* __restrict__ xcb)
{
    __shared__ float WT[64 * 64];  // WT[ci][co]
    __shared__ float bs[64];
    int n = blockIdx.x, tid = threadIdx.x;
    int p = blockIdx.y * 256 + tid;  // tv index
    for (int i = tid; i < 4096; i += 256) WT[(i & 63) * 64 + (i >> 6)] = Wc[i];
    if (tid < 64) bs[tid] = bc[tid];
    __syncthreads();

    float acc[64];
#pragma unroll
    for (int c = 0; c < 64; c++) acc[c] = bs[c];
#pragma unroll 4
    for (int ci = 0; ci < 64; ci++) {
        float xv = x[((size_t)n * 64 + ci) * 4096 + p];
        const float4* wr = (const float4*)&WT[ci * 64];
#pragma unroll
        for (int q = 0; q < 16; q++) {
            float4 w4 = wr[q];
            acc[q * 4 + 0] = fmaf(w4.x, xv, acc[q * 4 + 0]);
            acc[q * 4 + 1] = fmaf(w4.y, xv, acc[q * 4 + 1]);
            acc[q * 4 + 2] = fmaf(w4.z, xv, acc[q * 4 + 2]);
            acc[q * 4 + 3] = fmaf(w4.w, xv, acc[q * 4 + 3]);
        }
    }
#pragma unroll
    for (int c = 0; c < 64; c++)
        xcb[((size_t)n * 64 + c) * 4096 + p] = __float2bfloat16(acc[c]);
}

// ---------------------------------------------------------------------------
// K3 (MFMA MLP): M'T[nl,c,w,v] = bf16( relu(MLP_sel(A[n,:,v,w])) * Dl[n,w] )
// One w per wave (branch-uniform). L1 vector fp32; L2 (K-padded to 32) and L3
// on mfma_f32_16x16x32_bf16. Weights/biases live in per-lane B/C fragments
// (VGPRs, loaded once). Activation transposes via wave-private LDS slices
// (72 B rows ~ conflict-free). No __syncthreads.
// grid (chunk, 64), block 256 = 4 waves = 4 w's; vc loop: 4 x 64 v-points.
__global__ __launch_bounds__(256) void k_mlp(
    const float* __restrict__ A, const float* __restrict__ hm,
    const float* __restrict__ Dsum,
    const float* __restrict__ nh_w1, const float* __restrict__ nh_b1,
    const float* __restrict__ nh_w2, const float* __restrict__ nh_b2,
    const float* __restrict__ nh_w3, const float* __restrict__ nh_b3,
    const float* __restrict__ h_w1, const float* __restrict__ h_b1,
    const float* __restrict__ h_w2, const float* __restrict__ h_b2,
    const float* __restrict__ h_w3, const float* __restrict__ h_b3,
    __hip_bfloat16* __restrict__ Mp, int n0)
{
    __shared__ uint2 lds[4 * 1152];  // per-wave 1152 uint2 (9216 B)
    int tid = threadIdx.x, lane = tid & 63, wid = tid >> 6;
    int nl = blockIdx.x, n = n0 + nl;
    int w = blockIdx.y * 4 + wid;
    int col = lane & 15, quad = lane >> 4;

    uint2* h1L = lds + wid * 1152;  // 64 rows x 9 uint2 (72 B)
    uint2* h2L = h1L + 576;         // 64 rows x 9 uint2

    int flag = (hm[n * 256 + w] > 0.5f) ? 1 : 0;
    flag = __builtin_amdgcn_readfirstlane(flag);
    const float* W1 = flag ? h_w1 : nh_w1;
    const float* B1 = flag ? h_b1 : nh_b1;
    const float* W2 = flag ? h_w2 : nh_w2;
    const float* B2 = flag ? h_b2 : nh_b2;
    const float* W3 = flag ? h_w3 : nh_w3;
    const float* B3 = flag ? h_b3 : nh_b3;

    float dl = 1.0f / (Dsum[n * 256 + w] + 0.001f);

    // --- B-fragments (weights) + C-init fragments (biases), loaded once ---
    // L2 as K=32 mfma with feats 16..31 zero-padded.
    U16B w2u[2]; f32x4 b2f[2];
#pragma unroll
    for (int ot = 0; ot < 2; ot++) {
#pragma unroll
        for (int j = 0; j < 8; j++) {
            int k = quad * 8 + j;
            w2u[ot].us[j] = (k < 16) ? f2bf(W2[(ot * 16 + col) * 16 + k]) : (unsigned short)0;
        }
#pragma unroll
        for (int r = 0; r < 4; r++) b2f[ot][r] = B2[ot * 16 + quad * 4 + r];
    }
    U16B w3u[4]; f32x4 b3f[4];
#pragma unroll
    for (int ot = 0; ot < 4; ot++) {
#pragma unroll
        for (int j = 0; j < 8; j++)
            w3u[ot].us[j] = f2bf(W3[(ot * 16 + col) * 32 + quad * 8 + j]);
#pragma unroll
        for (int r = 0; r < 4; r++) b3f[ot][r] = B3[ot * 16 + quad * 4 + r];
    }

    // zero h1 rows' padded feats 16..31 (bytes 32..63 -> uint2 idx 4..7), once
    uint2 z; z.x = 0; z.y = 0;
    h1L[lane * 9 + 4] = z; h1L[lane * 9 + 5] = z;
    h1L[lane * 9 + 6] = z; h1L[lane * 9 + 7] = z;

    unsigned short* mps = (unsigned short*)Mp;
    size_t mpBase = ((size_t)nl * 64) * 65536 + (size_t)w * 256;  // + c*65536 + v

    for (int vc = 0; vc < 4; vc++) {
        int v = vc * 64 + lane;
        float a[5];
#pragma unroll
        for (int k = 0; k < 5; k++)
            a[k] = A[(((size_t)n * 5 + k) * 256 + v) * 256 + w];

        float h1[16];
#pragma unroll
        for (int o = 0; o < 16; o++) {
            float s = B1[o];
#pragma unroll
            for (int k = 0; k < 5; k++) s = fmaf(W1[o * 5 + k], a[k], s);
            h1[o] = fmaxf(s, 0.f);
        }
        // lane's point -> row `lane` of h1L (feats 0..15, bytes 0..31)
#pragma unroll
        for (int i = 0; i < 4; i++) {
            uint2 pk;
            pk.x = packbf(h1[4 * i + 0], h1[4 * i + 1]);
            pk.y = packbf(h1[4 * i + 2], h1[4 * i + 3]);
            h1L[lane * 9 + i] = pk;
        }

#pragma unroll
        for (int pt = 0; pt < 4; pt++) {
            int row = pt * 16 + col;
            // L2: A-frag from h1L
            U16B af1;
            af1.u2[0] = h1L[row * 9 + quad * 2];
            af1.u2[1] = h1L[row * 9 + quad * 2 + 1];
            f32x4 acc0 = b2f[0], acc1 = b2f[1];
            acc0 = __builtin_amdgcn_mfma_f32_16x16x32_bf16(af1.s8, w2u[0].s8, acc0, 0, 0, 0);
            acc1 = __builtin_amdgcn_mfma_f32_16x16x32_bf16(af1.s8, w2u[1].s8, acc1, 0, 0, 0);
            // h2 (C-layout: col=pt-local, rows=feats quad*4+r [+16 for acc1])
            {
                uint2 pk;
                pk.x = packbf(fmaxf(acc0[0], 0.f), fmaxf(acc0[1], 0.f));
                pk.y = packbf(fmaxf(acc0[2], 0.f), fmaxf(acc0[3], 0.f));
                h2L[row * 9 + quad] = pk;
                pk.x = packbf(fmaxf(acc1[0], 0.f), fmaxf(acc1[1], 0.f));
                pk.y = packbf(fmaxf(acc1[2], 0.f), fmaxf(acc1[3], 0.f));
                h2L[row * 9 + 4 + quad] = pk;
            }
            // L3: A-frag from h2L
            U16B af2;
            af2.u2[0] = h2L[row * 9 + quad * 2];
            af2.u2[1] = h2L[row * 9 + quad * 2 + 1];
            int vout = vc * 64 + pt * 16 + col;
#pragma unroll
            for (int ot = 0; ot < 4; ot++) {
                f32x4 acc = b3f[ot];
                acc = __builtin_amdgcn_mfma_f32_16x16x32_bf16(af2.s8, w3u[ot].s8, acc, 0, 0, 0);
                size_t base = mpBase + (size_t)(ot * 16 + quad * 4) * 65536 + vout;
#pragma unroll
                for (int r = 0; r < 4; r++)
                    mps[base + (size_t)r * 65536] = f2bf(fmaxf(acc[r], 0.f) * dl);
            }
        }
    }
}

// ---------------------------------------------------------------------------
// K4 (MFMA): out[n,c,t,w] = sum_v xcb[n,c,t,v] * M'T[nl,c,w,v]
// grid (128, chunk): block = (c, w-half). 4 waves x 32 w each (2 w-tiles).
// 2048 blocks -> 8 blocks/CU -> 32 waves/CU for latency hiding.
__global__ __launch_bounds__(256) void k_gemm(const __hip_bfloat16* __restrict__ Mp,
                                              const __hip_bfloat16* __restrict__ xcb,
                                              float* __restrict__ out, int n0)
{
    int tid = threadIdx.x;
    int lane = tid & 63;
    int wid = tid >> 6;
    int bx = blockIdx.x;
    int wh = bx & 1, c = bx >> 1;
    int nl = blockIdx.y, n = n0 + nl;
    int col = lane & 15;
    int quad = lane >> 4;
    int w0 = wh * 128 + wid * 32;

    const short* xp = (const short*)xcb +
                      (((size_t)n * 64 + c) * 16 + col) * 256 + quad * 8;
    const short* bp = (const short*)Mp +
                      (((size_t)nl * 64 + c) * 256 + w0 + col) * 256 + quad * 8;

    f32x4 acc0 = {0.f, 0.f, 0.f, 0.f};
    f32x4 acc1 = {0.f, 0.f, 0.f, 0.f};
#pragma unroll
    for (int ks = 0; ks < 8; ks++) {
        short8 af = *(const short8*)(xp + ks * 32);
        short8 b0 = *(const short8*)(bp + ks * 32);
        short8 b1 = *(const short8*)(bp + 16 * 256 + ks * 32);
        acc0 = __builtin_amdgcn_mfma_f32_16x16x32_bf16(af, b0, acc0, 0, 0, 0);
        acc1 = __builtin_amdgcn_mfma_f32_16x16x32_bf16(af, b1, acc1, 0, 0, 0);
    }
#pragma unroll
    for (int r = 0; r < 4; r++) {
        size_t ob = (((size_t)n * 64 + c) * 16 + quad * 4 + r) * 256 + w0 + col;
        out[ob] = acc0[r];
        out[ob + 16] = acc1[r];
    }
}

// ---------------------------------------------------------------------------
extern "C" void kernel_launch(void* const* d_in, const int* in_sizes, int n_in,
                              void* d_out, int out_size, void* d_ws, size_t ws_size,
                              hipStream_t stream)
{
    const float* x      = (const float*)d_in[0];
    const float* A      = (const float*)d_in[1];
    const float* hmask  = (const float*)d_in[2];
    const float* conv_w = (const float*)d_in[4];
    const float* conv_b = (const float*)d_in[5];
    const float* nh_w1 = (const float*)d_in[6];
    const float* nh_b1 = (const float*)d_in[7];
    const float* nh_w2 = (const float*)d_in[8];
    const float* nh_b2 = (const float*)d_in[9];
    const float* nh_w3 = (const float*)d_in[10];
    const float* nh_b3 = (const float*)d_in[11];
    const float* h_w1 = (const float*)d_in[12];
    const float* h_b1 = (const float*)d_in[13];
    const float* h_w2 = (const float*)d_in[14];
    const float* h_b2 = (const float*)d_in[15];
    const float* h_w3 = (const float*)d_in[16];
    const float* h_b3 = (const float*)d_in[17];

    float* out  = (float*)d_out;
    float* outA = out + (size_t)NB * CC * TT * VV;

    float* Dsum = (float*)d_ws;                                   // 32 KB
    __hip_bfloat16* xcb = (__hip_bfloat16*)((char*)d_ws + 32768); // 16.8 MB
    size_t xcbBytes = (size_t)NB * CC * TT * VV * 2;
    __hip_bfloat16* Mp = (__hip_bfloat16*)((char*)d_ws + 32768 + xcbBytes);

    size_t perN = (size_t)CC * VV * VV * 2;  // 8,388,608 B per n
    size_t fixed = 32768 + xcbBytes;
    int chunk = 4;
    if (ws_size >= fixed + 16 * perN) chunk = 16;       // 134 MB M' — LLC-resident
    else if (ws_size >= fixed + 8 * perN) chunk = 8;

    hipMemsetAsync(Dsum, 0, NB * VV * sizeof(float), stream);
    k_copyAcs<<<dim3(NB, 40), 256, 0, stream>>>(A, outA, Dsum);
    k_xc<<<dim3(NB, 16), 256, 0, stream>>>(x, conv_w, conv_b, xcb);

    for (int n0 = 0; n0 < NB; n0 += chunk) {
        k_mlp<<<dim3(chunk, 64), 256, 0, stream>>>(
            A, hmask, Dsum,
            nh_w1, nh_b1, nh_w2, nh_b2, nh_w3, nh_b3,
            h_w1, h_b1, h_w2, h_b2, h_w3, h_b3, Mp, n0);
        k_gemm<<<dim3(128, chunk), 256, 0, stream>>>(Mp, xcb, out, n0);
    }
}

// Round 5
// 403.081 us; speedup vs baseline: 3.8224x; 1.0189x over previous
//
#include <hip/hip_runtime.h>
#include <hip/hip_bf16.h>
#include <cstddef>

#define NB 32
#define CC 64
#define TT 16
#define VV 256
#define KK 5

typedef __attribute__((ext_vector_type(8))) short short8;
typedef __attribute__((ext_vector_type(4))) float f32x4;

union U16B { short8 s8; uint2 u2[2]; uint4 u4; unsigned u[4]; unsigned short us[8]; };

__device__ inline unsigned short f2bf(float f) {
    unsigned u = __float_as_uint(f);
    return (unsigned short)((u + 0x7fffu + ((u >> 16) & 1u)) >> 16);
}
__device__ inline unsigned packbf(float a, float b) {
    return (unsigned)f2bf(a) | ((unsigned)f2bf(b) << 16);
}

// ---------------------------------------------------------------------------
// K1: copy A -> out tail AND Dsum[n][w] += column sums (A read once).
__global__ __launch_bounds__(256) void k_copyAcs(const float* __restrict__ A,
                                                 float* __restrict__ outA,
                                                 float* __restrict__ Dsum)
{
    int n = blockIdx.x, rb = blockIdx.y, w = threadIdx.x;
    size_t base = ((size_t)n * (KK * VV) + rb * 32) * VV;
    float s = 0.f;
#pragma unroll
    for (int i = 0; i < 32; i++) {
        float val = A[base + i * VV + w];
        outA[base + i * VV + w] = val;
        s += val;
    }
    atomicAdd(&Dsum[n * VV + w], s);
}

// ---------------------------------------------------------------------------
// K2: xcb[n,c,t,v] = bf16( sum_ci Wc[c,ci]*x[n,ci,t,v] + bc[c] )
__global__ __launch_bounds__(256) void k_xc(const float* __restrict__ x,
                                            const float* __restrict__ Wc,
                                            const float* __restrict__ bc,
                                            __hip_bfloat16* __restrict__ xcb)
{
    __shared__ float WT[64 * 64];  // WT[ci][co]
    __shared__ float bs[64];
    int n = blockIdx.x, tid = threadIdx.x;
    int p = blockIdx.y * 256 + tid;  // t*256+v index
    for (int i = tid; i < 4096; i += 256) WT[(i & 63) * 64 + (i >> 6)] = Wc[i];
    if (tid < 64) bs[tid] = bc[tid];
    __syncthreads();

    float acc[64];
#pragma unroll
    for (int c = 0; c < 64; c++) acc[c] = bs[c];
#pragma unroll 4
    for (int ci = 0; ci < 64; ci++) {
        float xv = x[((size_t)n * 64 + ci) * 4096 + p];
        const float4* wr = (const float4*)&WT[ci * 64];
#pragma unroll
        for (int q = 0; q < 16; q++) {
            float4 w4 = wr[q];
            acc[q * 4 + 0] = fmaf(w4.x, xv, acc[q * 4 + 0]);
            acc[q * 4 + 1] = fmaf(w4.y, xv, acc[q * 4 + 1]);
            acc[q * 4 + 2] = fmaf(w4.z, xv, acc[q * 4 + 2]);
            acc[q * 4 + 3] = fmaf(w4.w, xv, acc[q * 4 + 3]);
        }
    }
#pragma unroll
    for (int c = 0; c < 64; c++)
        xcb[((size_t)n * 64 + c) * 4096 + p] = __float2bfloat16(acc[c]);
}

// ---------------------------------------------------------------------------
// K3 fused: per block (n, 16-w tile). Per 16-v chunk:
//  Phase A: MLP -> M tile [64c][16w][16v] bf16 in LDS (M' never hits HBM)
//  Phase B: acc[c][t,w] += xcb . M via mfma (K upper half nulled via zero-block)
// LDS: 16B zero block + per-wave h1/h2 transpose slices + M tile = 80,912 B
#define H1RS 48
#define H2RS 72
#define HWAVE (64 * H1RS + 64 * H2RS)      // 7680
#define MS_WST 48                          // 16 v * 2B + 16 pad (16*odd -> uniform)
#define MS_CST (16 * MS_WST + 16)          // 784
#define LDS_H0 16
#define LDS_MS (LDS_H0 + 4 * HWAVE)        // 30736
#define LDS_TOTAL (LDS_MS + 64 * MS_CST)   // 80912

__global__ __launch_bounds__(256) void k_fuse(
    const float* __restrict__ A, const float* __restrict__ hm,
    const float* __restrict__ Dsum, const __hip_bfloat16* __restrict__ xcb,
    const float* __restrict__ nh_w1, const float* __restrict__ nh_b1,
    const float* __restrict__ nh_w2, const float* __restrict__ nh_b2,
    const float* __restrict__ nh_w3, const float* __restrict__ nh_b3,
    const float* __restrict__ h_w1, const float* __restrict__ h_b1,
    const float* __restrict__ h_w2, const float* __restrict__ h_b2,
    const float* __restrict__ h_w3, const float* __restrict__ h_b3,
    float* __restrict__ out)
{
    __shared__ char smem[LDS_TOTAL];
    int tid = threadIdx.x, lane = tid & 63, wid = tid >> 6;
    int n = blockIdx.x, wt = blockIdx.y;
    int col = lane & 15, quad = lane >> 4;
    int vl = col, wsel = quad;  // Phase A lane role: point (w = wid*4+wsel, v-local=vl)

    char* h1b = smem + LDS_H0 + wid * HWAVE;
    char* h2b = h1b + 64 * H1RS;
    unsigned short* Ms = (unsigned short*)(smem + LDS_MS);

    if (tid < 4) ((unsigned*)smem)[tid] = 0;  // shared 16B zero block

    int w_lane = wt * 16 + wid * 4 + wsel;
    bool flag_lane = hm[n * 256 + w_lane] > 0.5f;

    // group (per-pt) branch flags + degree-norm scalars (wave-uniform)
    bool fg[4]; float dlg[4];
#pragma unroll
    for (int g = 0; g < 4; g++) {
        int wg = wt * 16 + wid * 4 + g;
        fg[g] = hm[n * 256 + wg] > 0.5f;
        dlg[g] = 1.f / (Dsum[n * 256 + wg] + 0.001f);
    }

    // --- weight fragments for BOTH branches (VGPR-resident, loaded once) ---
    U16B w2u_n[2], w2u_h[2], w3u_n[4], w3u_h[4];
    f32x4 b2f_n[2], b2f_h[2], b3f_n[4], b3f_h[4];
#pragma unroll
    for (int ot = 0; ot < 2; ot++) {
#pragma unroll
        for (int j = 0; j < 8; j++) {
            int k = quad * 8 + j;
            w2u_n[ot].us[j] = (k < 16) ? f2bf(nh_w2[(ot * 16 + col) * 16 + k]) : (unsigned short)0;
            w2u_h[ot].us[j] = (k < 16) ? f2bf(h_w2[(ot * 16 + col) * 16 + k]) : (unsigned short)0;
        }
#pragma unroll
        for (int r = 0; r < 4; r++) {
            b2f_n[ot][r] = nh_b2[ot * 16 + quad * 4 + r];
            b2f_h[ot][r] = h_b2[ot * 16 + quad * 4 + r];
        }
    }
#pragma unroll
    for (int ot = 0; ot < 4; ot++) {
#pragma unroll
        for (int j = 0; j < 8; j++) {
            w3u_n[ot].us[j] = f2bf(nh_w3[(ot * 16 + col) * 32 + quad * 8 + j]);
            w3u_h[ot].us[j] = f2bf(h_w3[(ot * 16 + col) * 32 + quad * 8 + j]);
        }
#pragma unroll
        for (int r = 0; r < 4; r++) {
            b3f_n[ot][r] = nh_b3[ot * 16 + quad * 4 + r];
            b3f_h[ot][r] = h_b3[ot * 16 + quad * 4 + r];
        }
    }

    f32x4 acc[16];
#pragma unroll
    for (int i = 0; i < 16; i++) acc[i] = f32x4{0.f, 0.f, 0.f, 0.f};

    __syncthreads();  // zero block visible

    for (int vc = 0; vc < 16; vc++) {
        // ================= Phase A: MLP -> M-LDS =================
        {
            int v = vc * 16 + vl;
            float a[5];
#pragma unroll
            for (int k = 0; k < 5; k++)
                a[k] = A[(((size_t)n * 5 + k) * 256 + v) * 256 + w_lane];
            float h1s[16];
#pragma unroll
            for (int o = 0; o < 16; o++) {
                float sn = nh_b1[o], sh = h_b1[o];
#pragma unroll
                for (int k = 0; k < 5; k++) {
                    sn = fmaf(nh_w1[o * 5 + k], a[k], sn);
                    sh = fmaf(h_w1[o * 5 + k], a[k], sh);
                }
                h1s[o] = flag_lane ? fmaxf(sh, 0.f) : fmaxf(sn, 0.f);
            }
            uint4 q0, q1;
            q0.x = packbf(h1s[0], h1s[1]);  q0.y = packbf(h1s[2], h1s[3]);
            q0.z = packbf(h1s[4], h1s[5]);  q0.w = packbf(h1s[6], h1s[7]);
            q1.x = packbf(h1s[8], h1s[9]);  q1.y = packbf(h1s[10], h1s[11]);
            q1.z = packbf(h1s[12], h1s[13]); q1.w = packbf(h1s[14], h1s[15]);
            *(uint4*)(h1b + lane * H1RS) = q0;
            *(uint4*)(h1b + lane * H1RS + 16) = q1;

#pragma unroll
            for (int pt = 0; pt < 4; pt++) {
                int row = pt * 16 + col;
                U16B af1;
                {
                    const char* p1 = (quad < 2) ? (h1b + row * H1RS + quad * 16) : smem;
                    af1.u4 = *(const uint4*)p1;
                }
                // L2+L3 body with branch-selected (wave-uniform) weight sets
                auto body = [&](const U16B (&w2u)[2], const f32x4 (&b2f)[2],
                                const U16B (&w3u)[4], const f32x4 (&b3f)[4], float dl) {
                    f32x4 a0 = b2f[0], a1 = b2f[1];
                    a0 = __builtin_amdgcn_mfma_f32_16x16x32_bf16(af1.s8, w2u[0].s8, a0, 0, 0, 0);
                    a1 = __builtin_amdgcn_mfma_f32_16x16x32_bf16(af1.s8, w2u[1].s8, a1, 0, 0, 0);
                    uint2 pk;
                    pk.x = packbf(fmaxf(a0[0], 0.f), fmaxf(a0[1], 0.f));
                    pk.y = packbf(fmaxf(a0[2], 0.f), fmaxf(a0[3], 0.f));
                    *(uint2*)(h2b + row * H2RS + quad * 8) = pk;
                    pk.x = packbf(fmaxf(a1[0], 0.f), fmaxf(a1[1], 0.f));
                    pk.y = packbf(fmaxf(a1[2], 0.f), fmaxf(a1[3], 0.f));
                    *(uint2*)(h2b + row * H2RS + 32 + quad * 8) = pk;
                    U16B af2;
                    af2.u2[0] = *(const uint2*)(h2b + row * H2RS + quad * 16);
                    af2.u2[1] = *(const uint2*)(h2b + row * H2RS + quad * 16 + 8);
#pragma unroll
                    for (int ot = 0; ot < 4; ot++) {
                        f32x4 a3 = b3f[ot];
                        a3 = __builtin_amdgcn_mfma_f32_16x16x32_bf16(af2.s8, w3u[ot].s8, a3, 0, 0, 0);
#pragma unroll
                        for (int r = 0; r < 4; r++) {
                            int c = ot * 16 + quad * 4 + r;
                            Ms[c * (MS_CST / 2) + (wid * 4 + pt) * (MS_WST / 2) + col] =
                                f2bf(fmaxf(a3[r], 0.f) * dl);
                        }
                    }
                };
                if (fg[pt]) body(w2u_h, b2f_h, w3u_h, b3f_h, dlg[pt]);
                else        body(w2u_n, b2f_n, w3u_n, b3f_n, dlg[pt]);
            }
        }
        __syncthreads();  // M tile ready
        // ================= Phase B: contraction =================
        {
            const short* xbase = (const short*)xcb +
                (((size_t)n * 64) * 16 + col) * 256 + vc * 16 + (quad & 1) * 8;
#pragma unroll
            for (int cl = 0; cl < 16; cl++) {
                int c = wid * 16 + cl;
                short8 af = *(const short8*)(xbase + (size_t)c * 4096);
                const char* bp = (quad < 2)
                    ? (const char*)(smem + LDS_MS + c * MS_CST + col * MS_WST + quad * 16)
                    : (const char*)smem;  // zero block nulls k>=16
                U16B bf; bf.u4 = *(const uint4*)bp;
                acc[cl] = __builtin_amdgcn_mfma_f32_16x16x32_bf16(af, bf.s8, acc[cl], 0, 0, 0);
            }
        }
        __syncthreads();  // before next vc overwrites M
    }

    // epilogue: D col = w, rows quad*4+r = t (R3-verified convention)
#pragma unroll
    for (int cl = 0; cl < 16; cl++) {
        int c = wid * 16 + cl;
#pragma unroll
        for (int r = 0; r < 4; r++)
            out[(((size_t)n * 64 + c) * 16 + quad * 4 + r) * 256 + wt * 16 + col] =
                acc[cl][r];
    }
}

// ---------------------------------------------------------------------------
extern "C" void kernel_launch(void* const* d_in, const int* in_sizes, int n_in,
                              void* d_out, int out_size, void* d_ws, size_t ws_size,
                              hipStream_t stream)
{
    const float* x      = (const float*)d_in[0];
    const float* A      = (const float*)d_in[1];
    const float* hmask  = (const float*)d_in[2];
    const float* conv_w = (const float*)d_in[4];
    const float* conv_b = (const float*)d_in[5];
    const float* nh_w1 = (const float*)d_in[6];
    const float* nh_b1 = (const float*)d_in[7];
    const float* nh_w2 = (const float*)d_in[8];
    const float* nh_b2 = (const float*)d_in[9];
    const float* nh_w3 = (const float*)d_in[10];
    const float* nh_b3 = (const float*)d_in[11];
    const float* h_w1 = (const float*)d_in[12];
    const float* h_b1 = (const float*)d_in[13];
    const float* h_w2 = (const float*)d_in[14];
    const float* h_b2 = (const float*)d_in[15];
    const float* h_w3 = (const float*)d_in[16];
    const float* h_b3 = (const float*)d_in[17];

    float* out  = (float*)d_out;
    float* outA = out + (size_t)NB * CC * TT * VV;

    float* Dsum = (float*)d_ws;                                    // 32 KB
    __hip_bfloat16* xcb = (__hip_bfloat16*)((char*)d_ws + 32768);  // 16.8 MB

    hipMemsetAsync(Dsum, 0, NB * VV * sizeof(float), stream);
    k_copyAcs<<<dim3(NB, 40), 256, 0, stream>>>(A, outA, Dsum);
    k_xc<<<dim3(NB, 16), 256, 0, stream>>>(x, conv_w, conv_b, xcb);
    k_fuse<<<dim3(NB, 16), 256, 0, stream>>>(
        A, hmask, Dsum, xcb,
        nh_w1, nh_b1, nh_w2, nh_b2, nh_w3, nh_b3,
        h_w1, h_b1, h_w2, h_b2, h_w3, h_b3, out);
}